// Round 1
// baseline (2887.358 us; speedup 1.0000x reference)
//
#include <hip/hip_runtime.h>
#include <stdint.h>

#define BB 4
#define NN 16384
#define NPOINT 1024
#define NSAMPLE 32
#define CC 64
#define RADIUS2 0.00999999977648258209228515625f
#define BIGF 1.0e10f

// ---------------- repack w1 (64x67) -> (64x68) padded, pad=0 ----------------
__global__ __launch_bounds__(256) void repack_w1(const float* __restrict__ w1,
                                                 float* __restrict__ w1p) {
    int t = threadIdx.x;
    for (int i = t; i < 64 * 68; i += 256) {
        int o = i / 68, c = i % 68;
        w1p[i] = (c < 67) ? w1[o * 67 + c] : 0.0f;
    }
}

// ---------------- FPS: one 1024-thread block per batch ----------------
__global__ __launch_bounds__(1024) void fps_kernel(const float* __restrict__ xyz,
                                                   float* __restrict__ new_xyz) {
    const int b = blockIdx.x;
    const int t = threadIdx.x;
    const int lane = t & 63;
    const int w = t >> 6;  // 0..15

    __shared__ float scx, scy, scz;
    __shared__ int sfar;
    __shared__ float rv[16];
    __shared__ int ri[16];

    const float* xb = xyz + (size_t)b * NN * 3;

    float px[16], py[16], pz[16], dd[16];
#pragma unroll
    for (int j = 0; j < 16; ++j) {
        int gi = j * 1024 + t;
        px[j] = xb[gi * 3 + 0];
        py[j] = xb[gi * 3 + 1];
        pz[j] = xb[gi * 3 + 2];
        dd[j] = BIGF;
    }
    if (t == 0) sfar = 0;
    __syncthreads();

    for (int i = 0; i < NPOINT; ++i) {
        if (t == 0) {
            int f = sfar;
            float cx = xb[f * 3 + 0], cy = xb[f * 3 + 1], cz = xb[f * 3 + 2];
            scx = cx; scy = cy; scz = cz;
            float* o = new_xyz + ((size_t)b * NPOINT + i) * 3;
            o[0] = cx; o[1] = cy; o[2] = cz;
        }
        __syncthreads();
        float cx = scx, cy = scy, cz = scz;

        float bv = -1.0f;
        int bi = 0x7fffffff;
#pragma unroll
        for (int j = 0; j < 16; ++j) {
            // EXACT numpy order, no fma: (dx*dx + dy*dy) + dz*dz
            float dx = __fsub_rn(px[j], cx);
            float dy = __fsub_rn(py[j], cy);
            float dz = __fsub_rn(pz[j], cz);
            float d = __fadd_rn(__fadd_rn(__fmul_rn(dx, dx), __fmul_rn(dy, dy)),
                                __fmul_rn(dz, dz));
            float nd = fminf(dd[j], d);
            dd[j] = nd;
            // local indices ascend with j, so strict > keeps first occurrence
            if (nd > bv) { bv = nd; bi = j * 1024 + t; }
        }
        // wave argmax reduce, first-index tie-break
#pragma unroll
        for (int off = 32; off > 0; off >>= 1) {
            float ov = __shfl_down(bv, off);
            int oi = __shfl_down(bi, off);
            if (ov > bv || (ov == bv && oi < bi)) { bv = ov; bi = oi; }
        }
        if (lane == 0) { rv[w] = bv; ri[w] = bi; }
        __syncthreads();
        if (w == 0) {
            float v = (lane < 16) ? rv[lane] : -1.0f;
            int ix = (lane < 16) ? ri[lane] : 0x7fffffff;
#pragma unroll
            for (int off = 8; off > 0; off >>= 1) {
                float ov = __shfl_down(v, off);
                int oi = __shfl_down(ix, off);
                if (ov > v || (ov == v && oi < ix)) { v = ov; ix = oi; }
            }
            if (lane == 0) sfar = ix;
        }
        // no extra sync: thread 0 wrote sfar itself; top-of-loop sync orders scx
    }
}

// ---------------- ball query: one wave per centroid ----------------
__global__ __launch_bounds__(256) void ballquery_kernel(const float* __restrict__ xyz,
                                                        const float* __restrict__ new_xyz,
                                                        int* __restrict__ nidx) {
    const int t = threadIdx.x;
    const int lane = t & 63;
    const int w = t >> 6;
    const int cid = blockIdx.x * 4 + w;  // 0..4095
    const int b = cid >> 10;

    __shared__ int list[4][NSAMPLE];

    const float* xb = xyz + (size_t)b * NN * 3;
    const float* c = new_xyz + (size_t)cid * 3;
    float cx = c[0], cy = c[1], cz = c[2];

    int cnt = 0;
    for (int base = 0; base < NN && cnt < NSAMPLE; base += 64) {
        int j = base + lane;
        float dx = __fsub_rn(xb[j * 3 + 0], cx);
        float dy = __fsub_rn(xb[j * 3 + 1], cy);
        float dz = __fsub_rn(xb[j * 3 + 2], cz);
        float d2 = __fadd_rn(__fadd_rn(__fmul_rn(dx, dx), __fmul_rn(dy, dy)),
                             __fmul_rn(dz, dz));
        bool hit = d2 < RADIUS2;
        unsigned long long m = __ballot(hit);
        int pre = __popcll(m & ((1ull << lane) - 1ull));
        if (hit) {
            int pos = cnt + pre;
            if (pos < NSAMPLE) list[w][pos] = j;
        }
        cnt += __popcll(m);  // ballot result uniform -> cnt stays wave-uniform
    }
    __syncthreads();
    if (lane < NSAMPLE) {
        int first = list[w][0];  // >=1 hit always: centroid is a member point
        int v = (lane < cnt) ? list[w][lane] : first;
        nidx[(size_t)cid * NSAMPLE + lane] = v;
    }
}

// ---------------- grouped MLP + maxpool: one thread per (point,sample) ------
__global__ __launch_bounds__(256, 2) void mlp_kernel(
    const float* __restrict__ xyz, const float* __restrict__ features,
    const float* __restrict__ new_xyz, const int* __restrict__ nidx,
    const float* __restrict__ w1p, const float* __restrict__ b1,
    const float* __restrict__ w2, const float* __restrict__ b2,
    const float* __restrict__ w3, const float* __restrict__ b3,
    float* __restrict__ out) {
    const int gid = blockIdx.x * 256 + threadIdx.x;
    const int s = gid & 31;
    const int pg = gid >> 5;  // b*1024 + p
    const int b = pg >> 10;
    const int p = pg & 1023;

    const int idx = nidx[gid];
    const float* nc = new_xyz + (size_t)pg * 3;
    const float* pt = xyz + ((size_t)b * NN + idx) * 3;
    float gx = pt[0] - nc[0], gy = pt[1] - nc[1], gz = pt[2] - nc[2];

    float fin[64];
    const float4* fp = (const float4*)(features + ((size_t)b * NN + idx) * CC);
#pragma unroll
    for (int j = 0; j < 16; ++j) {
        float4 q = fp[j];
        fin[4 * j] = q.x; fin[4 * j + 1] = q.y;
        fin[4 * j + 2] = q.z; fin[4 * j + 3] = q.w;
    }

    float h1[64];
#pragma unroll
    for (int o = 0; o < 64; ++o) {
        const float4* wr = (const float4*)(w1p + o * 68);  // uniform -> s_load
        float acc = b1[o];
        float4 q0 = wr[0];
        acc = fmaf(q0.x, gx, acc);
        acc = fmaf(q0.y, gy, acc);
        acc = fmaf(q0.z, gz, acc);
        acc = fmaf(q0.w, fin[0], acc);
#pragma unroll
        for (int j = 1; j < 17; ++j) {
            float4 q = wr[j];
            int c0 = 4 * j - 3;
            acc = fmaf(q.x, fin[c0], acc);
            acc = fmaf(q.y, fin[c0 + 1], acc);
            acc = fmaf(q.z, fin[c0 + 2], acc);
            if (c0 + 3 < 64) acc = fmaf(q.w, fin[c0 + 3], acc);
        }
        h1[o] = fmaxf(acc, 0.0f);
    }

    float h2[64];
#pragma unroll
    for (int o = 0; o < 64; ++o) {
        const float4* wr = (const float4*)(w2 + o * 64);
        float acc = b2[o];
#pragma unroll
        for (int j = 0; j < 16; ++j) {
            float4 q = wr[j];
            acc = fmaf(q.x, h1[4 * j], acc);
            acc = fmaf(q.y, h1[4 * j + 1], acc);
            acc = fmaf(q.z, h1[4 * j + 2], acc);
            acc = fmaf(q.w, h1[4 * j + 3], acc);
        }
        h2[o] = fmaxf(acc, 0.0f);
    }

    float* ob = out + (size_t)b * 128 * NPOINT + p;
#pragma unroll
    for (int o = 0; o < 128; ++o) {
        const float4* wr = (const float4*)(w3 + o * 64);
        float acc = b3[o];
#pragma unroll
        for (int j = 0; j < 16; ++j) {
            float4 q = wr[j];
            acc = fmaf(q.x, h2[4 * j], acc);
            acc = fmaf(q.y, h2[4 * j + 1], acc);
            acc = fmaf(q.z, h2[4 * j + 2], acc);
            acc = fmaf(q.w, h2[4 * j + 3], acc);
        }
        float r = fmaxf(acc, 0.0f);
        // max over 32 samples = half-wave butterfly (stays within 32-groups)
#pragma unroll
        for (int off = 1; off < 32; off <<= 1) {
            float orr = __shfl_xor(r, off);
            r = fmaxf(r, orr);
        }
        if (s == 0) ob[(size_t)o * NPOINT] = r;
    }
}

extern "C" void kernel_launch(void* const* d_in, const int* in_sizes, int n_in,
                              void* d_out, int out_size, void* d_ws, size_t ws_size,
                              hipStream_t stream) {
    const float* xyz = (const float*)d_in[0];
    const float* features = (const float*)d_in[1];
    const float* w1 = (const float*)d_in[2];
    const float* b1 = (const float*)d_in[3];
    const float* w2 = (const float*)d_in[4];
    const float* b2 = (const float*)d_in[5];
    const float* w3 = (const float*)d_in[6];
    const float* b3 = (const float*)d_in[7];

    float* out = (float*)d_out;
    float* new_xyz = out;                          // B*NPOINT*3
    float* new_feat = out + BB * NPOINT * 3;       // B*128*NPOINT

    int* nidx = (int*)d_ws;                        // B*NPOINT*NSAMPLE ints
    float* w1p = (float*)((char*)d_ws + (size_t)BB * NPOINT * NSAMPLE * sizeof(int));

    hipLaunchKernelGGL(repack_w1, dim3(1), dim3(256), 0, stream, w1, w1p);
    hipLaunchKernelGGL(fps_kernel, dim3(BB), dim3(1024), 0, stream, xyz, new_xyz);
    hipLaunchKernelGGL(ballquery_kernel, dim3(BB * NPOINT / 4), dim3(256), 0, stream,
                       xyz, new_xyz, nidx);
    hipLaunchKernelGGL(mlp_kernel, dim3(BB * NPOINT * NSAMPLE / 256), dim3(256), 0, stream,
                       xyz, features, new_xyz, nidx, w1p, b1, w2, b2, w3, b3, new_feat);
}

// Round 2
// 2570.708 us; speedup vs baseline: 1.1232x; 1.1232x over previous
//
#include <hip/hip_runtime.h>
#include <stdint.h>

#define BB 4
#define NN 16384
#define NPOINT 1024
#define NSAMPLE 32
#define CC 64
#define RADIUS2 0.00999999977648258209228515625f
#define BIGF 1.0e10f

#define FT 512   // fps threads per block (8 waves)
#define FP 32    // points per thread (FT*FP == NN)

// ---------------- repack w1 (64x67) -> (64x68) padded, pad=0 ----------------
__global__ __launch_bounds__(256) void repack_w1(const float* __restrict__ w1,
                                                 float* __restrict__ w1p) {
    int t = threadIdx.x;
    for (int i = t; i < 64 * 68; i += 256) {
        int o = i / 68, c = i % 68;
        w1p[i] = (c < 67) ? w1[o * 67 + c] : 0.0f;
    }
}

// ---------------- FPS: one 512-thread block per batch, 1 barrier/iter -------
__global__ __launch_bounds__(FT, 2) void fps_kernel(const float* __restrict__ xyz,
                                                    float* __restrict__ new_xyz) {
    const int b = blockIdx.x;
    const int t = threadIdx.x;
    const int lane = t & 63;
    const int w = t >> 6;  // 0..7

    __shared__ float bufv[2][8];
    __shared__ int bufi[2][8];

    const float* xb = xyz + (size_t)b * NN * 3;

    float px[FP], py[FP], pz[FP], dd[FP];
#pragma unroll
    for (int j = 0; j < FP; ++j) {
        int gi = j * FT + t;
        px[j] = xb[gi * 3 + 0];
        py[j] = xb[gi * 3 + 1];
        pz[j] = xb[gi * 3 + 2];
        dd[j] = BIGF;
    }
    // initial centroid = point 0 (reference: farthest starts at 0)
    float cx = xb[0], cy = xb[1], cz = xb[2];

    for (int i = 0; i < NPOINT; ++i) {
        if (t == 0) {
            float* o = new_xyz + ((size_t)b * NPOINT + i) * 3;
            o[0] = cx; o[1] = cy; o[2] = cz;
        }
        float bv = -1.0f;
        int bj = 0;  // local point slot of best; candidates are inline consts
#pragma unroll
        for (int j = 0; j < FP; ++j) {
            // EXACT numpy order, no fma: (dx*dx + dy*dy) + dz*dz
            float dx = __fsub_rn(px[j], cx);
            float dy = __fsub_rn(py[j], cy);
            float dz = __fsub_rn(pz[j], cz);
            float d = __fadd_rn(__fadd_rn(__fmul_rn(dx, dx), __fmul_rn(dy, dy)),
                                __fmul_rn(dz, dz));
            float nd = fminf(dd[j], d);
            dd[j] = nd;
            // j ascends -> strict > keeps first occurrence (global idx = j*FT+t,
            // monotone in j for fixed t)
            bool c = nd > bv;
            bv = c ? nd : bv;
            bj = c ? j : bj;
        }
        int bi = bj * FT + t;  // global index; for fixed value, smaller t wins ties below

        // wave argmax reduce, first-index tie-break
#pragma unroll
        for (int off = 32; off > 0; off >>= 1) {
            float ov = __shfl_down(bv, off);
            int oi = __shfl_down(bi, off);
            if (ov > bv || (ov == bv && oi < bi)) { bv = ov; bi = oi; }
        }
        if (lane == 0) { bufv[i & 1][w] = bv; bufi[i & 1][w] = bi; }
        __syncthreads();

        // every lane loads one of the 8 wave results (broadcast read), then a
        // 3-step xor butterfly within each 8-lane group -> ALL lanes get the
        // global argmax. No second barrier needed.
        float v = bufv[i & 1][lane & 7];
        int ix = bufi[i & 1][lane & 7];
#pragma unroll
        for (int off = 1; off < 8; off <<= 1) {
            float ov = __shfl_xor(v, off);
            int oi = __shfl_xor(ix, off);
            if (ov > v || (ov == v && oi < ix)) { v = ov; ix = oi; }
        }
        // all threads fetch next centroid coords (uniform address, L1 hit)
        cx = xb[ix * 3 + 0];
        cy = xb[ix * 3 + 1];
        cz = xb[ix * 3 + 2];
    }
}

// ---------------- ball query: one wave per centroid ----------------
__global__ __launch_bounds__(256) void ballquery_kernel(const float* __restrict__ xyz,
                                                        const float* __restrict__ new_xyz,
                                                        int* __restrict__ nidx) {
    const int t = threadIdx.x;
    const int lane = t & 63;
    const int w = t >> 6;
    const int cid = blockIdx.x * 4 + w;  // 0..4095
    const int b = cid >> 10;

    __shared__ int list[4][NSAMPLE];

    const float* xb = xyz + (size_t)b * NN * 3;
    const float* c = new_xyz + (size_t)cid * 3;
    float cx = c[0], cy = c[1], cz = c[2];

    int cnt = 0;
    for (int base = 0; base < NN && cnt < NSAMPLE; base += 64) {
        int j = base + lane;
        float dx = __fsub_rn(xb[j * 3 + 0], cx);
        float dy = __fsub_rn(xb[j * 3 + 1], cy);
        float dz = __fsub_rn(xb[j * 3 + 2], cz);
        float d2 = __fadd_rn(__fadd_rn(__fmul_rn(dx, dx), __fmul_rn(dy, dy)),
                             __fmul_rn(dz, dz));
        bool hit = d2 < RADIUS2;
        unsigned long long m = __ballot(hit);
        int pre = __popcll(m & ((1ull << lane) - 1ull));
        if (hit) {
            int pos = cnt + pre;
            if (pos < NSAMPLE) list[w][pos] = j;
        }
        cnt += __popcll(m);  // ballot result uniform -> cnt stays wave-uniform
    }
    __syncthreads();
    if (lane < NSAMPLE) {
        int first = list[w][0];  // >=1 hit always: centroid is a member point
        int v = (lane < cnt) ? list[w][lane] : first;
        nidx[(size_t)cid * NSAMPLE + lane] = v;
    }
}

// ---------------- grouped MLP + maxpool: one thread per (point,sample) ------
__global__ __launch_bounds__(256, 2) void mlp_kernel(
    const float* __restrict__ xyz, const float* __restrict__ features,
    const float* __restrict__ new_xyz, const int* __restrict__ nidx,
    const float* __restrict__ w1p, const float* __restrict__ b1,
    const float* __restrict__ w2, const float* __restrict__ b2,
    const float* __restrict__ w3, const float* __restrict__ b3,
    float* __restrict__ out) {
    const int gid = blockIdx.x * 256 + threadIdx.x;
    const int s = gid & 31;
    const int pg = gid >> 5;  // b*1024 + p
    const int b = pg >> 10;
    const int p = pg & 1023;

    const int idx = nidx[gid];
    const float* nc = new_xyz + (size_t)pg * 3;
    const float* pt = xyz + ((size_t)b * NN + idx) * 3;
    float gx = pt[0] - nc[0], gy = pt[1] - nc[1], gz = pt[2] - nc[2];

    float fin[64];
    const float4* fp = (const float4*)(features + ((size_t)b * NN + idx) * CC);
#pragma unroll
    for (int j = 0; j < 16; ++j) {
        float4 q = fp[j];
        fin[4 * j] = q.x; fin[4 * j + 1] = q.y;
        fin[4 * j + 2] = q.z; fin[4 * j + 3] = q.w;
    }

    float h1[64];
#pragma unroll
    for (int o = 0; o < 64; ++o) {
        const float4* wr = (const float4*)(w1p + o * 68);  // uniform -> s_load
        float acc = b1[o];
        float4 q0 = wr[0];
        acc = fmaf(q0.x, gx, acc);
        acc = fmaf(q0.y, gy, acc);
        acc = fmaf(q0.z, gz, acc);
        acc = fmaf(q0.w, fin[0], acc);
#pragma unroll
        for (int j = 1; j < 17; ++j) {
            float4 q = wr[j];
            int c0 = 4 * j - 3;
            acc = fmaf(q.x, fin[c0], acc);
            acc = fmaf(q.y, fin[c0 + 1], acc);
            acc = fmaf(q.z, fin[c0 + 2], acc);
            if (c0 + 3 < 64) acc = fmaf(q.w, fin[c0 + 3], acc);
        }
        h1[o] = fmaxf(acc, 0.0f);
    }

    float h2[64];
#pragma unroll
    for (int o = 0; o < 64; ++o) {
        const float4* wr = (const float4*)(w2 + o * 64);
        float acc = b2[o];
#pragma unroll
        for (int j = 0; j < 16; ++j) {
            float4 q = wr[j];
            acc = fmaf(q.x, h1[4 * j], acc);
            acc = fmaf(q.y, h1[4 * j + 1], acc);
            acc = fmaf(q.z, h1[4 * j + 2], acc);
            acc = fmaf(q.w, h1[4 * j + 3], acc);
        }
        h2[o] = fmaxf(acc, 0.0f);
    }

    float* ob = out + (size_t)b * 128 * NPOINT + p;
#pragma unroll
    for (int o = 0; o < 128; ++o) {
        const float4* wr = (const float4*)(w3 + o * 64);
        float acc = b3[o];
#pragma unroll
        for (int j = 0; j < 16; ++j) {
            float4 q = wr[j];
            acc = fmaf(q.x, h2[4 * j], acc);
            acc = fmaf(q.y, h2[4 * j + 1], acc);
            acc = fmaf(q.z, h2[4 * j + 2], acc);
            acc = fmaf(q.w, h2[4 * j + 3], acc);
        }
        float r = fmaxf(acc, 0.0f);
        // max over 32 samples = half-wave butterfly (stays within 32-groups)
#pragma unroll
        for (int off = 1; off < 32; off <<= 1) {
            float orr = __shfl_xor(r, off);
            r = fmaxf(r, orr);
        }
        if (s == 0) ob[(size_t)o * NPOINT] = r;
    }
}

extern "C" void kernel_launch(void* const* d_in, const int* in_sizes, int n_in,
                              void* d_out, int out_size, void* d_ws, size_t ws_size,
                              hipStream_t stream) {
    const float* xyz = (const float*)d_in[0];
    const float* features = (const float*)d_in[1];
    const float* w1 = (const float*)d_in[2];
    const float* b1 = (const float*)d_in[3];
    const float* w2 = (const float*)d_in[4];
    const float* b2 = (const float*)d_in[5];
    const float* w3 = (const float*)d_in[6];
    const float* b3 = (const float*)d_in[7];

    float* out = (float*)d_out;
    float* new_xyz = out;                          // B*NPOINT*3
    float* new_feat = out + BB * NPOINT * 3;       // B*128*NPOINT

    int* nidx = (int*)d_ws;                        // B*NPOINT*NSAMPLE ints
    float* w1p = (float*)((char*)d_ws + (size_t)BB * NPOINT * NSAMPLE * sizeof(int));

    hipLaunchKernelGGL(repack_w1, dim3(1), dim3(256), 0, stream, w1, w1p);
    hipLaunchKernelGGL(fps_kernel, dim3(BB), dim3(FT), 0, stream, xyz, new_xyz);
    hipLaunchKernelGGL(ballquery_kernel, dim3(BB * NPOINT / 4), dim3(256), 0, stream,
                       xyz, new_xyz, nidx);
    hipLaunchKernelGGL(mlp_kernel, dim3(BB * NPOINT * NSAMPLE / 256), dim3(256), 0, stream,
                       xyz, features, new_xyz, nidx, w1p, b1, w2, b2, w3, b3, new_feat);
}